// Round 6
// baseline (297.456 us; speedup 1.0000x reference)
//
#include <hip/hip_runtime.h>
#include <hip/hip_bf16.h>

typedef unsigned short u16;
typedef __attribute__((ext_vector_type(8))) short short8;   // 8 bf16 = 4 VGPR
typedef __attribute__((ext_vector_type(4))) float f32x4;

#define NBLK 512     // mega grid: 2 blocks/CU on 256 CUs, co-resident by construction
#define MAXC 512

__device__ __forceinline__ float b2f(u16 b) {
    return __uint_as_float(((unsigned)b) << 16);
}
// fp32 -> bf16 RNE (matches R5's passing numerics exactly)
__device__ __forceinline__ u16 f2b(float f) {
    unsigned u = __float_as_uint(f);
    return (u16)((u + 0x7FFFu + ((u >> 16) & 1u)) >> 16);
}
__device__ __forceinline__ short8 load_cvt8(const float* __restrict__ p) {
    float4 f0 = *(const float4*)p;
    float4 f1 = *(const float4*)(p + 4);
    short8 r;
    r[0] = (short)f2b(f0.x); r[1] = (short)f2b(f0.y);
    r[2] = (short)f2b(f0.z); r[3] = (short)f2b(f0.w);
    r[4] = (short)f2b(f1.x); r[5] = (short)f2b(f1.y);
    r[6] = (short)f2b(f1.z); r[7] = (short)f2b(f1.w);
    return r;
}

// ---------------------------------------------------------------------------
// K0 prep: blocks [0,192) clear the 2MB mask; blocks [192,256) compute
// per-block ORs of the edge buffer's odd int32 words -> orbuf[0..63]
// (all-zero <=> int64 layout). Block 0 also re-arms the grid-barrier words
// (ws is poisoned once before timing; every call must self-initialize).
// ---------------------------------------------------------------------------
__global__ __launch_bounds__(256) void prep_kernel(
    const int* __restrict__ e, int E,
    uint4* __restrict__ maskv, int mask16,
    unsigned* __restrict__ orbuf, unsigned* __restrict__ bar)
{
    int b = blockIdx.x, t = threadIdx.x;
    if (b == 0 && t < 2) bar[t] = 0u;
    if (b < 192) {
        uint4 z = {0u, 0u, 0u, 0u};
        for (int i = b * 256 + t; i < mask16; i += 192 * 256) maskv[i] = z;
    } else {
        int bb = b - 192;
        unsigned acc = 0;
        for (int i = bb * 256 + t; i < E; i += 64 * 256)
            acc |= (unsigned)e[2 * i + 1];
        __shared__ unsigned red[4];
        #pragma unroll
        for (int o = 32; o > 0; o >>= 1) acc |= __shfl_xor(acc, o, 64);
        if ((t & 63) == 0) red[t >> 6] = acc;
        __syncthreads();
        if (t == 0) orbuf[bb] = red[0] | red[1] | red[2] | red[3];
    }
}

// ---------------------------------------------------------------------------
// Grid barrier: arrival counter + generation word, agent scope (per-XCD L2s
// are not coherent -> every access via __hip_atomic_* AGENT + threadfence).
// Co-residency of all NBLK blocks is guaranteed (2/CU, LDS/VGPR headroom),
// so no deadlock; bounded spin turns any surprise into a visible wrong
// answer instead of a hang.
// ---------------------------------------------------------------------------
__device__ __forceinline__ void gridbar(unsigned* bar) {
    __syncthreads();
    if (threadIdx.x == 0) {
        unsigned* cnt = bar;
        unsigned* gen = bar + 1;
        unsigned g = __hip_atomic_load(gen, __ATOMIC_RELAXED, __HIP_MEMORY_SCOPE_AGENT);
        __threadfence();   // release this block's phase writes
        unsigned arrived = __hip_atomic_fetch_add(cnt, 1u, __ATOMIC_ACQ_REL,
                                                  __HIP_MEMORY_SCOPE_AGENT);
        if (arrived == NBLK - 1) {
            __hip_atomic_store(cnt, 0u, __ATOMIC_RELAXED, __HIP_MEMORY_SCOPE_AGENT);
            __hip_atomic_fetch_add(gen, 1u, __ATOMIC_RELEASE, __HIP_MEMORY_SCOPE_AGENT);
        } else {
            long spins = 0;
            while (__hip_atomic_load(gen, __ATOMIC_ACQUIRE,
                                     __HIP_MEMORY_SCOPE_AGENT) == g) {
                __builtin_amdgcn_s_sleep(1);
                if (++spins > (1L << 24)) break;   // failsafe
            }
        }
        __threadfence();   // acquire side for the whole CU
    }
    __syncthreads();
}

// ---------------------------------------------------------------------------
// K1 mega: phase1 scatter(128 blk) || QKV-MFMA(384 blk) -> bar ->
//          phase2 attn (8 rows/block)                   -> bar ->
//          phase3 final MFMA (512 tiles of 64 rows x 32 cols)
// LDS phases overlap via union (max 33.8 KB -> 2 blocks/CU fits easily).
// ---------------------------------------------------------------------------
union SMemU {
    u16 wq[64][264];                              // qkv W tile (33792 B)
    struct { int cols[MAXC]; int wtot[2]; } at;   // attn (2056 B)
    u16 wf[32][520];                              // final W tile (33280 B)
};

__global__ __launch_bounds__(256, 2) void mega_kernel(
    const int* __restrict__ e, int E, int N,
    unsigned* __restrict__ mask, const unsigned* __restrict__ orbuf,
    unsigned* __restrict__ bar,
    const float* __restrict__ x,
    const float* __restrict__ Wq, const float* __restrict__ Wk,
    const float* __restrict__ Wv,
    const float* __restrict__ bq, const float* __restrict__ bk,
    const float* __restrict__ bv,
    const float* __restrict__ Wp, const float* __restrict__ bp,
    u16* __restrict__ q, u16* __restrict__ k, u16* __restrict__ v,
    u16* __restrict__ y, float* __restrict__ out)
{
    __shared__ SMemU sm;
    int t = threadIdx.x;
    int nw = N >> 5;                               // 128 mask words / row

    // ================= phase 1: scatter || qkv =================
    if (blockIdx.x < 128) {
        unsigned oo = orbuf[t & 63];
        #pragma unroll
        for (int o = 32; o > 0; o >>= 1) oo |= __shfl_xor(oo, o, 64);
        bool i32mode = (oo != 0);
        for (int i = blockIdx.x * 256 + t; i < E; i += 128 * 256) {
            int row, col;
            if (i32mode) { row = e[i];     col = e[E + i]; }
            else         { row = e[2 * i]; col = e[2 * E + 2 * i]; }
            if ((unsigned)row < (unsigned)N && (unsigned)col < (unsigned)N)
                atomicOr(&mask[(size_t)row * nw + (col >> 5)], 1u << (col & 31));
        }
    } else {
        int bid = blockIdx.x - 128;                // 0..383
        int bx = bid & 31, by = bid >> 5;          // 32 row tiles x 12 col tiles
        int which = by >> 2;                       // 0=q 1=k 2=v
        int ncl = (by & 3) * 64;
        const float* Ws   = (which == 0) ? Wq : (which == 1) ? Wk : Wv;
        const float* bias = (which == 0) ? bq : (which == 1) ? bk : bv;
        u16*         T    = (which == 0) ? q  : (which == 1) ? k  : v;

        for (int s = t; s < 4096; s += 256) {
            int r  = s >> 6;
            int c4 = (s & 63) << 2;
            float4 f = *(const float4*)&Ws[(size_t)(ncl + r) * 256 + c4];
            sm.wq[r][c4 + 0] = f2b(f.x); sm.wq[r][c4 + 1] = f2b(f.y);
            sm.wq[r][c4 + 2] = f2b(f.z); sm.wq[r][c4 + 3] = f2b(f.w);
        }
        __syncthreads();

        int wv = t >> 6, l = t & 63, lr = l & 15, lk = l >> 4;
        int m0 = bx * 128 + wv * 32;
        f32x4 acc[2][4] = {};
        const float* a0b = x + (size_t)(m0 + lr) * 256 + lk * 8;
        const float* a1b = a0b + 16 * 256;

        #pragma unroll
        for (int kk = 0; kk < 8; kk++) {
            short8 a0 = load_cvt8(a0b + kk * 32);
            short8 a1 = load_cvt8(a1b + kk * 32);
            #pragma unroll
            for (int j = 0; j < 4; j++) {
                short8 b = *(const short8*)&sm.wq[j * 16 + lr][lk * 8 + kk * 32];
                acc[0][j] = __builtin_amdgcn_mfma_f32_16x16x32_bf16(a0, b, acc[0][j], 0, 0, 0);
                acc[1][j] = __builtin_amdgcn_mfma_f32_16x16x32_bf16(a1, b, acc[1][j], 0, 0, 0);
            }
        }
        #pragma unroll
        for (int i2 = 0; i2 < 2; i2++)
            #pragma unroll
            for (int j = 0; j < 4; j++)
                #pragma unroll
                for (int r = 0; r < 4; r++) {
                    int grow = m0 + i2 * 16 + lk * 4 + r;
                    int gc   = ncl + j * 16 + lr;
                    T[(size_t)grow * 256 + gc] = f2b(acc[i2][j][r] + bias[gc]);
                }
    }
    gridbar(bar);

    // ================= phase 2: attn, 8 rows per block =================
    {
        int lane = t & 63, wv = t >> 6;
        int h = t >> 5, jl = t & 31;
        const float scale = 0.17677669529663687f;   // 1/sqrt(32)

        for (int r8 = 0; r8 < 8; r8++) {
            int n = blockIdx.x * 8 + r8;

            unsigned word = 0; int pc = 0;
            if (t < nw) { word = mask[(size_t)n * nw + t]; pc = __popc(word); }
            int scan = pc;
            #pragma unroll
            for (int o = 1; o < 64; o <<= 1) {
                int ot = __shfl_up(scan, o, 64);
                if (lane >= o) scan += ot;
            }
            if (wv < 2 && lane == 63) sm.at.wtot[wv] = scan;
            __syncthreads();
            if (t < nw) {
                int off = (wv == 1 ? sm.at.wtot[0] : 0) + scan - pc;
                unsigned w = word;
                while (w && off < MAXC) {
                    int b = __ffs(w) - 1;
                    w &= w - 1;
                    sm.at.cols[off++] = (t << 5) + b;
                }
            }
            int cnt = sm.at.wtot[0] + sm.at.wtot[1];
            if (cnt > MAXC) cnt = MAXC;
            __syncthreads();

            float qreg[32];
            const short8* qp = (const short8*)(q + (size_t)n * 256 + h * 32);
            #pragma unroll
            for (int i = 0; i < 4; i++) {
                short8 s = qp[i];
                #pragma unroll
                for (int e2 = 0; e2 < 8; e2++) qreg[i * 8 + e2] = b2f((u16)s[e2]);
            }

            float mx = -1e30f, lsm = 0.f, acc = 0.f;
            for (int c0 = 0; c0 < cnt; c0 += 64) {
                int cc = min(64, cnt - c0);
                float s0 = -1e30f, s1 = -1e30f;
                if (jl < cc) {
                    const short8* kp = (const short8*)(k + (size_t)sm.at.cols[c0 + jl] * 256 + h * 32);
                    float sa = 0.f;
                    #pragma unroll
                    for (int i = 0; i < 4; i++) {
                        short8 s = kp[i];
                        #pragma unroll
                        for (int e2 = 0; e2 < 8; e2++)
                            sa = fmaf(b2f((u16)s[e2]), qreg[i * 8 + e2], sa);
                    }
                    s0 = sa * scale;
                }
                if (jl + 32 < cc) {
                    const short8* kp = (const short8*)(k + (size_t)sm.at.cols[c0 + jl + 32] * 256 + h * 32);
                    float sa = 0.f;
                    #pragma unroll
                    for (int i = 0; i < 4; i++) {
                        short8 s = kp[i];
                        #pragma unroll
                        for (int e2 = 0; e2 < 8; e2++)
                            sa = fmaf(b2f((u16)s[e2]), qreg[i * 8 + e2], sa);
                    }
                    s1 = sa * scale;
                }

                float cm = fmaxf(s0, s1);
                #pragma unroll
                for (int o = 16; o > 0; o >>= 1) cm = fmaxf(cm, __shfl_xor(cm, o, 32));
                float mnew = fmaxf(mx, cm);
                float f  = __expf(mx - mnew);
                float w0 = (jl < cc)      ? __expf(s0 - mnew) : 0.f;
                float w1 = (jl + 32 < cc) ? __expf(s1 - mnew) : 0.f;
                float ls = w0 + w1;
                #pragma unroll
                for (int o = 16; o > 0; o >>= 1) ls += __shfl_xor(ls, o, 32);
                lsm = lsm * f + ls;
                mx  = mnew;
                acc *= f;

                int e1 = min(cc, 32);
                int j = 0;
                for (; j + 4 <= e1; j += 4) {
                    float v0 = b2f(v[(size_t)sm.at.cols[c0 + j + 0] * 256 + t]);
                    float v1 = b2f(v[(size_t)sm.at.cols[c0 + j + 1] * 256 + t]);
                    float v2 = b2f(v[(size_t)sm.at.cols[c0 + j + 2] * 256 + t]);
                    float v3 = b2f(v[(size_t)sm.at.cols[c0 + j + 3] * 256 + t]);
                    acc = fmaf(__shfl(w0, j + 0, 32), v0, acc);
                    acc = fmaf(__shfl(w0, j + 1, 32), v1, acc);
                    acc = fmaf(__shfl(w0, j + 2, 32), v2, acc);
                    acc = fmaf(__shfl(w0, j + 3, 32), v3, acc);
                }
                for (; j < e1; j++)
                    acc = fmaf(__shfl(w0, j, 32), b2f(v[(size_t)sm.at.cols[c0 + j] * 256 + t]), acc);
                for (j = 32; j + 4 <= cc; j += 4) {
                    float v0 = b2f(v[(size_t)sm.at.cols[c0 + j + 0] * 256 + t]);
                    float v1 = b2f(v[(size_t)sm.at.cols[c0 + j + 1] * 256 + t]);
                    float v2 = b2f(v[(size_t)sm.at.cols[c0 + j + 2] * 256 + t]);
                    float v3 = b2f(v[(size_t)sm.at.cols[c0 + j + 3] * 256 + t]);
                    acc = fmaf(__shfl(w1, j - 32, 32), v0, acc);
                    acc = fmaf(__shfl(w1, j - 31, 32), v1, acc);
                    acc = fmaf(__shfl(w1, j - 30, 32), v2, acc);
                    acc = fmaf(__shfl(w1, j - 29, 32), v3, acc);
                }
                for (; j < cc; j++)
                    acc = fmaf(__shfl(w1, j - 32, 32), b2f(v[(size_t)sm.at.cols[c0 + j] * 256 + t]), acc);
            }

            y[(size_t)n * 256 + t] = f2b((cnt > 0) ? acc / lsm : 0.f);
            __syncthreads();           // WAR guard on sm.at before next row
        }
    }
    gridbar(bar);

    // ================= phase 3: final GEMM, 64 rows x 32 cols =================
    {
        int rt = blockIdx.x >> 3, ct = blockIdx.x & 7;
        int n0 = ct * 32;

        for (int s = t; s < 4096; s += 256) {
            int r  = s >> 7;              // 0..31
            int c4 = (s & 127) << 2;      // 0..508
            float4 f = *(const float4*)&Wp[(size_t)(n0 + r) * 512 + c4];
            sm.wf[r][c4 + 0] = f2b(f.x); sm.wf[r][c4 + 1] = f2b(f.y);
            sm.wf[r][c4 + 2] = f2b(f.z); sm.wf[r][c4 + 3] = f2b(f.w);
        }
        __syncthreads();

        int wv = t >> 6, l = t & 63, lr = l & 15, lk = l >> 4;
        int m0 = rt * 64 + wv * 16;
        f32x4 acc[2] = {};
        const float* axb = x + (size_t)(m0 + lr) * 256 + lk * 8;
        const u16*   ayb = y + (size_t)(m0 + lr) * 256 + lk * 8;

        #pragma unroll
        for (int kk = 0; kk < 16; kk++) {
            short8 a;
            if (kk < 8) a = load_cvt8(axb + kk * 32);
            else        a = *(const short8*)(ayb + (kk - 8) * 32);
            #pragma unroll
            for (int j = 0; j < 2; j++) {
                short8 b = *(const short8*)&sm.wf[j * 16 + lr][lk * 8 + kk * 32];
                acc[j] = __builtin_amdgcn_mfma_f32_16x16x32_bf16(a, b, acc[j], 0, 0, 0);
            }
        }
        #pragma unroll
        for (int j = 0; j < 2; j++)
            #pragma unroll
            for (int r = 0; r < 4; r++) {
                int grow = m0 + lk * 4 + r;
                int gc   = n0 + j * 16 + lr;
                out[(size_t)grow * 256 + gc] = acc[j][r] + bp[gc];
            }
    }
}

// ---------------------------------------------------------------------------
extern "C" void kernel_launch(void* const* d_in, const int* in_sizes, int n_in,
                              void* d_out, int out_size, void* d_ws, size_t ws_size,
                              hipStream_t stream) {
    const float* x  = (const float*)d_in[0];
    const int*   ei = (const int*)d_in[1];
    const float* Wq = (const float*)d_in[2];
    const float* bq = (const float*)d_in[3];
    const float* Wk = (const float*)d_in[4];
    const float* bk = (const float*)d_in[5];
    const float* Wv = (const float*)d_in[6];
    const float* bv = (const float*)d_in[7];
    const float* Wp = (const float*)d_in[8];
    const float* bp = (const float*)d_in[9];
    float* out = (float*)d_out;

    const int D = 256;
    int N = in_sizes[0] / D;       // 4096
    int E = in_sizes[1] / 2;       // 135168

    size_t maskB = (size_t)N * (N >> 5) * sizeof(unsigned);   // 2 MB
    char* ws = (char*)d_ws;
    unsigned* mask  = (unsigned*)ws;
    unsigned* orbuf = (unsigned*)(ws + maskB);                // 64 words
    unsigned* bar   = (unsigned*)(ws + maskB + 256);          // cnt, gen
    u16* qbb = (u16*)(ws + maskB + 512);
    u16* kbb = qbb + (size_t)N * D;
    u16* vbb = kbb + (size_t)N * D;
    u16* ybb = vbb + (size_t)N * D;

    prep_kernel<<<256, 256, 0, stream>>>(ei, E, (uint4*)ws, (int)(maskB / 16),
                                         orbuf, bar);

    mega_kernel<<<NBLK, 256, 0, stream>>>(
        ei, E, N, mask, orbuf, bar, x, Wq, Wk, Wv, bq, bk, bv, Wp, bp,
        qbb, kbb, vbb, ybb, out);
}

// Round 7
// 202.707 us; speedup vs baseline: 1.4674x; 1.4674x over previous
//
#include <hip/hip_runtime.h>
#include <hip/hip_bf16.h>

typedef unsigned short u16;
typedef __attribute__((ext_vector_type(8))) short short8;   // 8 bf16 = 4 VGPR
typedef __attribute__((ext_vector_type(4))) float f32x4;

#define NBLK 512     // mega grid: 2 blocks/CU on 256 CUs, co-resident by construction
#define MAXC 512

__device__ __forceinline__ float b2f(u16 b) {
    return __uint_as_float(((unsigned)b) << 16);
}
// fp32 -> bf16 RNE (matches R5's passing numerics exactly)
__device__ __forceinline__ u16 f2b(float f) {
    unsigned u = __float_as_uint(f);
    return (u16)((u + 0x7FFFu + ((u >> 16) & 1u)) >> 16);
}
__device__ __forceinline__ short8 load_cvt8(const float* __restrict__ p) {
    float4 f0 = *(const float4*)p;
    float4 f1 = *(const float4*)(p + 4);
    short8 r;
    r[0] = (short)f2b(f0.x); r[1] = (short)f2b(f0.y);
    r[2] = (short)f2b(f0.z); r[3] = (short)f2b(f0.w);
    r[4] = (short)f2b(f1.x); r[5] = (short)f2b(f1.y);
    r[6] = (short)f2b(f1.z); r[7] = (short)f2b(f1.w);
    return r;
}

// ---------------------------------------------------------------------------
// K0 prep: blocks [0,192) clear the 2MB mask; blocks [192,256) compute
// per-block ORs of the edge buffer's odd int32 words -> orbuf[0..63]
// (all-zero <=> int64 layout). Block 0 also re-arms the grid-barrier words
// (ws is poisoned once before timing; every call must self-initialize).
// ---------------------------------------------------------------------------
__global__ __launch_bounds__(256) void prep_kernel(
    const int* __restrict__ e, int E,
    uint4* __restrict__ maskv, int mask16,
    unsigned* __restrict__ orbuf, unsigned* __restrict__ bar)
{
    int b = blockIdx.x, t = threadIdx.x;
    if (b == 0 && t < 2) bar[t] = 0u;
    if (b < 192) {
        uint4 z = {0u, 0u, 0u, 0u};
        for (int i = b * 256 + t; i < mask16; i += 192 * 256) maskv[i] = z;
    } else {
        int bb = b - 192;
        unsigned acc = 0;
        for (int i = bb * 256 + t; i < E; i += 64 * 256)
            acc |= (unsigned)e[2 * i + 1];
        __shared__ unsigned red[4];
        #pragma unroll
        for (int o = 32; o > 0; o >>= 1) acc |= __shfl_xor(acc, o, 64);
        if ((t & 63) == 0) red[t >> 6] = acc;
        __syncthreads();
        if (t == 0) orbuf[bb] = red[0] | red[1] | red[2] | red[3];
    }
}

// ---------------------------------------------------------------------------
// Grid barrier v2. R6's version spun on an ACQUIRE agent-scope load: every
// probe emits a cache-invalidate (remote-L2 lines), and 511 spinners
// produced a continuous invalidation storm that evicted the working blocks'
// data -> 297us collapse. Fix: spin on a RELAXED agent load (coherent, no
// invalidate) with s_sleep(8) between probes; issue ONE acquire fence after
// the generation change is observed. Winner publishes via release store.
// Co-residency of all NBLK blocks is guaranteed (2/CU); bounded spin turns
// any surprise into a visible wrong answer instead of a hang.
// ---------------------------------------------------------------------------
__device__ __forceinline__ void gridbar(unsigned* bar) {
    __syncthreads();
    if (threadIdx.x == 0) {
        unsigned* cnt = bar;
        unsigned* gen = bar + 1;
        unsigned g = __hip_atomic_load(gen, __ATOMIC_RELAXED, __HIP_MEMORY_SCOPE_AGENT);
        // ACQ_REL RMW: releases this block's phase writes; on the last
        // arriver it also synchronizes with every other block's release.
        unsigned arrived = __hip_atomic_fetch_add(cnt, 1u, __ATOMIC_ACQ_REL,
                                                  __HIP_MEMORY_SCOPE_AGENT);
        if (arrived == NBLK - 1) {
            __hip_atomic_store(cnt, 0u, __ATOMIC_RELAXED, __HIP_MEMORY_SCOPE_AGENT);
            __hip_atomic_store(gen, g + 1u, __ATOMIC_RELEASE, __HIP_MEMORY_SCOPE_AGENT);
        } else {
            int spins = 0;
            while (__hip_atomic_load(gen, __ATOMIC_RELAXED,
                                     __HIP_MEMORY_SCOPE_AGENT) == g) {
                __builtin_amdgcn_s_sleep(8);          // ~512 cy between probes
                if (++spins > (1 << 20)) break;       // failsafe (~0.3s)
            }
            __builtin_amdgcn_fence(__ATOMIC_ACQUIRE, "agent");  // once, on exit
        }
    }
    __syncthreads();
}

// ---------------------------------------------------------------------------
// K1 mega: phase1 scatter(128 blk) || QKV-MFMA(384 blk) -> bar ->
//          phase2 attn (8 rows/block)                   -> bar ->
//          phase3 final MFMA (512 tiles of 64 rows x 32 cols)
// LDS phases overlap via union (max 33.8 KB -> 2 blocks/CU fits easily).
// ---------------------------------------------------------------------------
union SMemU {
    u16 wq[64][264];                              // qkv W tile (33792 B)
    struct { int cols[MAXC]; int wtot[2]; } at;   // attn (2056 B)
    u16 wf[32][520];                              // final W tile (33280 B)
};

__global__ __launch_bounds__(256, 2) void mega_kernel(
    const int* __restrict__ e, int E, int N,
    unsigned* __restrict__ mask, const unsigned* __restrict__ orbuf,
    unsigned* __restrict__ bar,
    const float* __restrict__ x,
    const float* __restrict__ Wq, const float* __restrict__ Wk,
    const float* __restrict__ Wv,
    const float* __restrict__ bq, const float* __restrict__ bk,
    const float* __restrict__ bv,
    const float* __restrict__ Wp, const float* __restrict__ bp,
    u16* __restrict__ q, u16* __restrict__ k, u16* __restrict__ v,
    u16* __restrict__ y, float* __restrict__ out)
{
    __shared__ SMemU sm;
    int t = threadIdx.x;
    int nw = N >> 5;                               // 128 mask words / row

    // ================= phase 1: scatter || qkv =================
    if (blockIdx.x < 128) {
        unsigned oo = orbuf[t & 63];
        #pragma unroll
        for (int o = 32; o > 0; o >>= 1) oo |= __shfl_xor(oo, o, 64);
        bool i32mode = (oo != 0);
        for (int i = blockIdx.x * 256 + t; i < E; i += 128 * 256) {
            int row, col;
            if (i32mode) { row = e[i];     col = e[E + i]; }
            else         { row = e[2 * i]; col = e[2 * E + 2 * i]; }
            if ((unsigned)row < (unsigned)N && (unsigned)col < (unsigned)N)
                atomicOr(&mask[(size_t)row * nw + (col >> 5)], 1u << (col & 31));
        }
    } else {
        int bid = blockIdx.x - 128;                // 0..383
        int bx = bid & 31, by = bid >> 5;          // 32 row tiles x 12 col tiles
        int which = by >> 2;                       // 0=q 1=k 2=v
        int ncl = (by & 3) * 64;
        const float* Ws   = (which == 0) ? Wq : (which == 1) ? Wk : Wv;
        const float* bias = (which == 0) ? bq : (which == 1) ? bk : bv;
        u16*         T    = (which == 0) ? q  : (which == 1) ? k  : v;

        for (int s = t; s < 4096; s += 256) {
            int r  = s >> 6;
            int c4 = (s & 63) << 2;
            float4 f = *(const float4*)&Ws[(size_t)(ncl + r) * 256 + c4];
            sm.wq[r][c4 + 0] = f2b(f.x); sm.wq[r][c4 + 1] = f2b(f.y);
            sm.wq[r][c4 + 2] = f2b(f.z); sm.wq[r][c4 + 3] = f2b(f.w);
        }
        __syncthreads();

        int wv = t >> 6, l = t & 63, lr = l & 15, lk = l >> 4;
        int m0 = bx * 128 + wv * 32;
        f32x4 acc[2][4] = {};
        const float* a0b = x + (size_t)(m0 + lr) * 256 + lk * 8;
        const float* a1b = a0b + 16 * 256;

        #pragma unroll
        for (int kk = 0; kk < 8; kk++) {
            short8 a0 = load_cvt8(a0b + kk * 32);
            short8 a1 = load_cvt8(a1b + kk * 32);
            #pragma unroll
            for (int j = 0; j < 4; j++) {
                short8 b = *(const short8*)&sm.wq[j * 16 + lr][lk * 8 + kk * 32];
                acc[0][j] = __builtin_amdgcn_mfma_f32_16x16x32_bf16(a0, b, acc[0][j], 0, 0, 0);
                acc[1][j] = __builtin_amdgcn_mfma_f32_16x16x32_bf16(a1, b, acc[1][j], 0, 0, 0);
            }
        }
        #pragma unroll
        for (int i2 = 0; i2 < 2; i2++)
            #pragma unroll
            for (int j = 0; j < 4; j++)
                #pragma unroll
                for (int r = 0; r < 4; r++) {
                    int grow = m0 + i2 * 16 + lk * 4 + r;
                    int gc   = ncl + j * 16 + lr;
                    T[(size_t)grow * 256 + gc] = f2b(acc[i2][j][r] + bias[gc]);
                }
    }
    gridbar(bar);

    // ================= phase 2: attn, 8 rows per block =================
    {
        int lane = t & 63, wv = t >> 6;
        int h = t >> 5, jl = t & 31;
        const float scale = 0.17677669529663687f;   // 1/sqrt(32)

        for (int r8 = 0; r8 < 8; r8++) {
            int n = blockIdx.x * 8 + r8;

            unsigned word = 0; int pc = 0;
            if (t < nw) { word = mask[(size_t)n * nw + t]; pc = __popc(word); }
            int scan = pc;
            #pragma unroll
            for (int o = 1; o < 64; o <<= 1) {
                int ot = __shfl_up(scan, o, 64);
                if (lane >= o) scan += ot;
            }
            if (wv < 2 && lane == 63) sm.at.wtot[wv] = scan;
            __syncthreads();
            if (t < nw) {
                int off = (wv == 1 ? sm.at.wtot[0] : 0) + scan - pc;
                unsigned w = word;
                while (w && off < MAXC) {
                    int b = __ffs(w) - 1;
                    w &= w - 1;
                    sm.at.cols[off++] = (t << 5) + b;
                }
            }
            int cnt = sm.at.wtot[0] + sm.at.wtot[1];
            if (cnt > MAXC) cnt = MAXC;
            __syncthreads();

            float qreg[32];
            const short8* qp = (const short8*)(q + (size_t)n * 256 + h * 32);
            #pragma unroll
            for (int i = 0; i < 4; i++) {
                short8 s = qp[i];
                #pragma unroll
                for (int e2 = 0; e2 < 8; e2++) qreg[i * 8 + e2] = b2f((u16)s[e2]);
            }

            float mx = -1e30f, lsm = 0.f, acc = 0.f;
            for (int c0 = 0; c0 < cnt; c0 += 64) {
                int cc = min(64, cnt - c0);
                float s0 = -1e30f, s1 = -1e30f;
                if (jl < cc) {
                    const short8* kp = (const short8*)(k + (size_t)sm.at.cols[c0 + jl] * 256 + h * 32);
                    float sa = 0.f;
                    #pragma unroll
                    for (int i = 0; i < 4; i++) {
                        short8 s = kp[i];
                        #pragma unroll
                        for (int e2 = 0; e2 < 8; e2++)
                            sa = fmaf(b2f((u16)s[e2]), qreg[i * 8 + e2], sa);
                    }
                    s0 = sa * scale;
                }
                if (jl + 32 < cc) {
                    const short8* kp = (const short8*)(k + (size_t)sm.at.cols[c0 + jl + 32] * 256 + h * 32);
                    float sa = 0.f;
                    #pragma unroll
                    for (int i = 0; i < 4; i++) {
                        short8 s = kp[i];
                        #pragma unroll
                        for (int e2 = 0; e2 < 8; e2++)
                            sa = fmaf(b2f((u16)s[e2]), qreg[i * 8 + e2], sa);
                    }
                    s1 = sa * scale;
                }

                float cm = fmaxf(s0, s1);
                #pragma unroll
                for (int o = 16; o > 0; o >>= 1) cm = fmaxf(cm, __shfl_xor(cm, o, 32));
                float mnew = fmaxf(mx, cm);
                float f  = __expf(mx - mnew);
                float w0 = (jl < cc)      ? __expf(s0 - mnew) : 0.f;
                float w1 = (jl + 32 < cc) ? __expf(s1 - mnew) : 0.f;
                float ls = w0 + w1;
                #pragma unroll
                for (int o = 16; o > 0; o >>= 1) ls += __shfl_xor(ls, o, 32);
                lsm = lsm * f + ls;
                mx  = mnew;
                acc *= f;

                int e1 = min(cc, 32);
                int j = 0;
                for (; j + 4 <= e1; j += 4) {
                    float v0 = b2f(v[(size_t)sm.at.cols[c0 + j + 0] * 256 + t]);
                    float v1 = b2f(v[(size_t)sm.at.cols[c0 + j + 1] * 256 + t]);
                    float v2 = b2f(v[(size_t)sm.at.cols[c0 + j + 2] * 256 + t]);
                    float v3 = b2f(v[(size_t)sm.at.cols[c0 + j + 3] * 256 + t]);
                    acc = fmaf(__shfl(w0, j + 0, 32), v0, acc);
                    acc = fmaf(__shfl(w0, j + 1, 32), v1, acc);
                    acc = fmaf(__shfl(w0, j + 2, 32), v2, acc);
                    acc = fmaf(__shfl(w0, j + 3, 32), v3, acc);
                }
                for (; j < e1; j++)
                    acc = fmaf(__shfl(w0, j, 32), b2f(v[(size_t)sm.at.cols[c0 + j] * 256 + t]), acc);
                for (j = 32; j + 4 <= cc; j += 4) {
                    float v0 = b2f(v[(size_t)sm.at.cols[c0 + j + 0] * 256 + t]);
                    float v1 = b2f(v[(size_t)sm.at.cols[c0 + j + 1] * 256 + t]);
                    float v2 = b2f(v[(size_t)sm.at.cols[c0 + j + 2] * 256 + t]);
                    float v3 = b2f(v[(size_t)sm.at.cols[c0 + j + 3] * 256 + t]);
                    acc = fmaf(__shfl(w1, j - 32, 32), v0, acc);
                    acc = fmaf(__shfl(w1, j - 31, 32), v1, acc);
                    acc = fmaf(__shfl(w1, j - 30, 32), v2, acc);
                    acc = fmaf(__shfl(w1, j - 29, 32), v3, acc);
                }
                for (; j < cc; j++)
                    acc = fmaf(__shfl(w1, j - 32, 32), b2f(v[(size_t)sm.at.cols[c0 + j] * 256 + t]), acc);
            }

            y[(size_t)n * 256 + t] = f2b((cnt > 0) ? acc / lsm : 0.f);
            __syncthreads();           // WAR guard on sm.at before next row
        }
    }
    gridbar(bar);

    // ================= phase 3: final GEMM, 64 rows x 32 cols =================
    {
        int rt = blockIdx.x >> 3, ct = blockIdx.x & 7;
        int n0 = ct * 32;

        for (int s = t; s < 4096; s += 256) {
            int r  = s >> 7;              // 0..31
            int c4 = (s & 127) << 2;      // 0..508
            float4 f = *(const float4*)&Wp[(size_t)(n0 + r) * 512 + c4];
            sm.wf[r][c4 + 0] = f2b(f.x); sm.wf[r][c4 + 1] = f2b(f.y);
            sm.wf[r][c4 + 2] = f2b(f.z); sm.wf[r][c4 + 3] = f2b(f.w);
        }
        __syncthreads();

        int wv = t >> 6, l = t & 63, lr = l & 15, lk = l >> 4;
        int m0 = rt * 64 + wv * 16;
        f32x4 acc[2] = {};
        const float* axb = x + (size_t)(m0 + lr) * 256 + lk * 8;
        const u16*   ayb = y + (size_t)(m0 + lr) * 256 + lk * 8;

        #pragma unroll
        for (int kk = 0; kk < 16; kk++) {
            short8 a;
            if (kk < 8) a = load_cvt8(axb + kk * 32);
            else        a = *(const short8*)(ayb + (kk - 8) * 32);
            #pragma unroll
            for (int j = 0; j < 2; j++) {
                short8 b = *(const short8*)&sm.wf[j * 16 + lr][lk * 8 + kk * 32];
                acc[j] = __builtin_amdgcn_mfma_f32_16x16x32_bf16(a, b, acc[j], 0, 0, 0);
            }
        }
        #pragma unroll
        for (int j = 0; j < 2; j++)
            #pragma unroll
            for (int r = 0; r < 4; r++) {
                int grow = m0 + lk * 4 + r;
                int gc   = n0 + j * 16 + lr;
                out[(size_t)grow * 256 + gc] = acc[j][r] + bp[gc];
            }
    }
}

// ---------------------------------------------------------------------------
extern "C" void kernel_launch(void* const* d_in, const int* in_sizes, int n_in,
                              void* d_out, int out_size, void* d_ws, size_t ws_size,
                              hipStream_t stream) {
    const float* x  = (const float*)d_in[0];
    const int*   ei = (const int*)d_in[1];
    const float* Wq = (const float*)d_in[2];
    const float* bq = (const float*)d_in[3];
    const float* Wk = (const float*)d_in[4];
    const float* bk = (const float*)d_in[5];
    const float* Wv = (const float*)d_in[6];
    const float* bv = (const float*)d_in[7];
    const float* Wp = (const float*)d_in[8];
    const float* bp = (const float*)d_in[9];
    float* out = (float*)d_out;

    const int D = 256;
    int N = in_sizes[0] / D;       // 4096
    int E = in_sizes[1] / 2;       // 135168

    size_t maskB = (size_t)N * (N >> 5) * sizeof(unsigned);   // 2 MB
    char* ws = (char*)d_ws;
    unsigned* mask  = (unsigned*)ws;
    unsigned* orbuf = (unsigned*)(ws + maskB);                // 64 words
    unsigned* bar   = (unsigned*)(ws + maskB + 256);          // cnt, gen
    u16* qbb = (u16*)(ws + maskB + 512);
    u16* kbb = qbb + (size_t)N * D;
    u16* vbb = kbb + (size_t)N * D;
    u16* ybb = vbb + (size_t)N * D;

    prep_kernel<<<256, 256, 0, stream>>>(ei, E, (uint4*)ws, (int)(maskB / 16),
                                         orbuf, bar);

    mega_kernel<<<NBLK, 256, 0, stream>>>(
        ei, E, N, mask, orbuf, bar, x, Wq, Wk, Wv, bq, bk, bv, Wp, bp,
        qbb, kbb, vbb, ybb, out);
}

// Round 8
// 51.692 us; speedup vs baseline: 5.7544x; 3.9214x over previous
//
#include <hip/hip_runtime.h>
#include <hip/hip_bf16.h>

typedef unsigned short u16;
typedef __attribute__((ext_vector_type(8))) short short8;   // 8 bf16 = 4 VGPR
typedef __attribute__((ext_vector_type(4))) float f32x4;

#define MAXC 256

__device__ __forceinline__ float b2f(u16 b) {
    return __uint_as_float(((unsigned)b) << 16);
}
// fp32 -> bf16 RNE (matches R5's passing numerics)
__device__ __forceinline__ u16 f2b(float f) {
    unsigned u = __float_as_uint(f);
    return (u16)((u + 0x7FFFu + ((u >> 16) & 1u)) >> 16);
}
__device__ __forceinline__ short8 load_cvt8(const float* __restrict__ p) {
    float4 f0 = *(const float4*)p;
    float4 f1 = *(const float4*)(p + 4);
    short8 r;
    r[0] = (short)f2b(f0.x); r[1] = (short)f2b(f0.y);
    r[2] = (short)f2b(f0.z); r[3] = (short)f2b(f0.w);
    r[4] = (short)f2b(f1.x); r[5] = (short)f2b(f1.y);
    r[6] = (short)f2b(f1.z); r[7] = (short)f2b(f1.w);
    return r;
}

// ---------------------------------------------------------------------------
// K1 prep, 3 roles: [0,192) clear 2MB mask; [192,256) detect int64 layout
// (per-block ORs of odd int32 words -> orbuf, all-zero <=> int64);
// [256,384) convert Wp fp32 -> bf16 (frees final_kernel of LDS staging).
// ---------------------------------------------------------------------------
__global__ __launch_bounds__(256) void prep_kernel(
    const int* __restrict__ e, int E,
    uint4* __restrict__ maskv, int mask16,
    unsigned* __restrict__ orbuf,
    const float* __restrict__ Wp, u16* __restrict__ wpb)
{
    int b = blockIdx.x, t = threadIdx.x;
    if (b < 192) {
        uint4 z = {0u, 0u, 0u, 0u};
        for (int i = b * 256 + t; i < mask16; i += 192 * 256) maskv[i] = z;
    } else if (b < 256) {
        int bb = b - 192;
        unsigned acc = 0;
        for (int i = bb * 256 + t; i < E; i += 64 * 256)
            acc |= (unsigned)e[2 * i + 1];
        __shared__ unsigned red[4];
        #pragma unroll
        for (int o = 32; o > 0; o >>= 1) acc |= __shfl_xor(acc, o, 64);
        if ((t & 63) == 0) red[t >> 6] = acc;
        __syncthreads();
        if (t == 0) orbuf[bb] = red[0] | red[1] | red[2] | red[3];
    } else {
        int i = (b - 256) * 256 + t;          // 0..32767 float4 slots (128K floats)
        float4 f = ((const float4*)Wp)[i];
        u16* d = wpb + 4 * (size_t)i;
        d[0] = f2b(f.x); d[1] = f2b(f.y); d[2] = f2b(f.z); d[3] = f2b(f.w);
    }
}

// ---------------------------------------------------------------------------
// K2 fused: blocks [0,128) scatter edges into the bitmask (atomicOr dedups,
// idempotent -> deterministic); blocks [128,512) QKV MFMA GEMM with
// on-the-fly fp32->bf16 conversion (W tile staged bf16 in LDS).
// ---------------------------------------------------------------------------
__global__ __launch_bounds__(256) void scatter_qkv_kernel(
    const int* __restrict__ e, int E, int N,
    unsigned* __restrict__ mask, const unsigned* __restrict__ orbuf,
    const float* __restrict__ x,
    const float* __restrict__ Wq, const float* __restrict__ Wk,
    const float* __restrict__ Wv,
    const float* __restrict__ bq, const float* __restrict__ bk,
    const float* __restrict__ bv,
    u16* __restrict__ q, u16* __restrict__ k, u16* __restrict__ v)
{
    __shared__ u16 Wl[64][264];
    int t = threadIdx.x;

    if (blockIdx.x < 128) {
        unsigned oo = orbuf[t & 63];
        #pragma unroll
        for (int o = 32; o > 0; o >>= 1) oo |= __shfl_xor(oo, o, 64);
        bool i32mode = (oo != 0);
        int nw = N >> 5;
        for (int i = blockIdx.x * 256 + t; i < E; i += 128 * 256) {
            int row, col;
            if (i32mode) { row = e[i];     col = e[E + i]; }
            else         { row = e[2 * i]; col = e[2 * E + 2 * i]; }
            if ((unsigned)row < (unsigned)N && (unsigned)col < (unsigned)N)
                atomicOr(&mask[(size_t)row * nw + (col >> 5)], 1u << (col & 31));
        }
        return;
    }

    int bid = blockIdx.x - 128;                // 0..383
    int bx = bid & 31, by = bid >> 5;          // 32 row tiles x 12 col tiles
    int which = by >> 2;                       // 0=q 1=k 2=v
    int ncl = (by & 3) * 64;
    const float* Ws   = (which == 0) ? Wq : (which == 1) ? Wk : Wv;
    const float* bias = (which == 0) ? bq : (which == 1) ? bk : bv;
    u16*         T    = (which == 0) ? q  : (which == 1) ? k  : v;

    for (int s = t; s < 4096; s += 256) {
        int r  = s >> 6;
        int c4 = (s & 63) << 2;
        float4 f = *(const float4*)&Ws[(size_t)(ncl + r) * 256 + c4];
        Wl[r][c4 + 0] = f2b(f.x); Wl[r][c4 + 1] = f2b(f.y);
        Wl[r][c4 + 2] = f2b(f.z); Wl[r][c4 + 3] = f2b(f.w);
    }
    __syncthreads();

    int wv = t >> 6, l = t & 63, lr = l & 15, lk = l >> 4;
    int m0 = bx * 128 + wv * 32;
    f32x4 acc[2][4] = {};
    const float* a0b = x + (size_t)(m0 + lr) * 256 + lk * 8;
    const float* a1b = a0b + 16 * 256;

    #pragma unroll
    for (int kk = 0; kk < 8; kk++) {
        short8 a0 = load_cvt8(a0b + kk * 32);
        short8 a1 = load_cvt8(a1b + kk * 32);
        #pragma unroll
        for (int j = 0; j < 4; j++) {
            short8 b = *(const short8*)&Wl[j * 16 + lr][lk * 8 + kk * 32];
            acc[0][j] = __builtin_amdgcn_mfma_f32_16x16x32_bf16(a0, b, acc[0][j], 0, 0, 0);
            acc[1][j] = __builtin_amdgcn_mfma_f32_16x16x32_bf16(a1, b, acc[1][j], 0, 0, 0);
        }
    }
    #pragma unroll
    for (int i2 = 0; i2 < 2; i2++)
        #pragma unroll
        for (int j = 0; j < 4; j++)
            #pragma unroll
            for (int r = 0; r < 4; r++) {
                int grow = m0 + i2 * 16 + lk * 4 + r;
                int gc   = ncl + j * 16 + lr;
                T[(size_t)grow * 256 + gc] = f2b(acc[i2][j][r] + bias[gc]);
            }
}

// ---------------------------------------------------------------------------
// K3 attn: ONE ROW PER WAVE (4096 independent wave-tasks; zero syncthreads).
// 1024 blocks x 256 thr: wave wv handles row blockIdx*4+wv.
//   compaction: 64 lanes read 128 mask words, wave shfl-scan, bit-extract
//               into per-wave cols[] (fixed lane-major order, deterministic).
//   scores:     lane (h8=lane>>4, jl=lane&15): dots for heads h8 & h8+4 of
//               neighbor jl, chunk=16; width-16 shuffle merge; online
//               softmax per head pair in registers.
//   V accum:    lane (hv=lane>>3) owns dims lane*4..+3; per-head w/f/lsum
//               passed via tiny per-wave LDS (explicit lgkmcnt waits).
// Occupancy: ~6.4KB LDS, ~70 VGPR -> 16 waves/CU; 16 rows in flight/CU
// (2x R5), shorter serial chain per row.
// ---------------------------------------------------------------------------
__global__ __launch_bounds__(256) void attn_kernel(
    const unsigned* __restrict__ mask,
    const u16* __restrict__ qb, const u16* __restrict__ kb,
    const u16* __restrict__ vb, u16* __restrict__ yb, int N)
{
    __shared__ int   cols[4][MAXC];
    __shared__ float ws[4][8][16];
    __shared__ float fs[4][8];
    __shared__ float lsums[4][8];

    int t = threadIdx.x;
    int wv = t >> 6, lane = t & 63;
    int n = blockIdx.x * 4 + wv;
    int nw = N >> 5;                        // 128

    // ---- per-wave compaction (fixed order -> deterministic) ----
    unsigned wa = mask[(size_t)n * nw + lane];
    unsigned wb = mask[(size_t)n * nw + 64 + lane];
    int pc = __popc(wa) + __popc(wb);
    int scan = pc;
    #pragma unroll
    for (int o = 1; o < 64; o <<= 1) {
        int pv = __shfl_up(scan, o, 64);
        if (lane >= o) scan += pv;
    }
    int cnt = __shfl(scan, 63, 64);
    if (cnt > MAXC) cnt = MAXC;
    int off = scan - pc;
    while (wa && off < MAXC) {
        int b = __ffs(wa) - 1; wa &= wa - 1;
        cols[wv][off++] = (lane << 5) + b;
    }
    while (wb && off < MAXC) {
        int b = __ffs(wb) - 1; wb &= wb - 1;
        cols[wv][off++] = ((64 + lane) << 5) + b;
    }
    asm volatile("s_waitcnt lgkmcnt(0)" ::: "memory");  // wave's LDS writes done

    int h8 = lane >> 4;                 // head pair (h8, h8+4)
    int jl = lane & 15;                 // neighbor slot in chunk
    int hv = lane >> 3;                 // V-phase head
    int d0 = lane * 4;                  // V-phase dims d0..d0+3

    const short8* qpA = (const short8*)(qb + (size_t)n * 256 + h8 * 32);
    const short8* qpB = (const short8*)(qb + (size_t)n * 256 + (h8 + 4) * 32);
    short8 qA0 = qpA[0], qA1 = qpA[1];
    short8 qB0 = qpB[0], qB1 = qpB[1];

    const float scale = 0.17677669529663687f;   // 1/sqrt(32)
    float mxA = -1e30f, mxB = -1e30f, lsA = 0.f, lsB = 0.f;
    float acc0 = 0.f, acc1 = 0.f, acc2 = 0.f, acc3 = 0.f;

    for (int c0 = 0; c0 < cnt; c0 += 16) {
        int cc = min(16, cnt - c0);
        float s0 = -1e30f, s1 = -1e30f;
        if (jl < cc) {
            const u16* kr = kb + (size_t)cols[wv][c0 + jl] * 256;
            short8 a0 = ((const short8*)(kr + h8 * 32))[0];
            short8 a1 = ((const short8*)(kr + h8 * 32))[1];
            short8 b0 = ((const short8*)(kr + (h8 + 4) * 32))[0];
            short8 b1 = ((const short8*)(kr + (h8 + 4) * 32))[1];
            float sa = 0.f, sb = 0.f;
            #pragma unroll
            for (int e2 = 0; e2 < 8; e2++) {
                sa = fmaf(b2f((u16)a0[e2]), b2f((u16)qA0[e2]), sa);
                sa = fmaf(b2f((u16)a1[e2]), b2f((u16)qA1[e2]), sa);
                sb = fmaf(b2f((u16)b0[e2]), b2f((u16)qB0[e2]), sb);
                sb = fmaf(b2f((u16)b1[e2]), b2f((u16)qB1[e2]), sb);
            }
            s0 = sa * scale; s1 = sb * scale;
        }
        // chunk max per head (width-16 groups)
        float cm0 = s0, cm1 = s1;
        #pragma unroll
        for (int o = 8; o > 0; o >>= 1) {
            cm0 = fmaxf(cm0, __shfl_xor(cm0, o, 16));
            cm1 = fmaxf(cm1, __shfl_xor(cm1, o, 16));
        }
        float mnA = fmaxf(mxA, cm0), mnB = fmaxf(mxB, cm1);
        float fA = __expf(mxA - mnA), fB = __expf(mxB - mnB);
        float w0 = (jl < cc) ? __expf(s0 - mnA) : 0.f;
        float w1 = (jl < cc) ? __expf(s1 - mnB) : 0.f;
        float t0 = w0, t1 = w1;
        #pragma unroll
        for (int o = 8; o > 0; o >>= 1) {
            t0 += __shfl_xor(t0, o, 16);
            t1 += __shfl_xor(t1, o, 16);
        }
        lsA = lsA * fA + t0;  lsB = lsB * fB + t1;
        mxA = mnA;            mxB = mnB;

        ws[wv][h8][jl]     = w0;
        ws[wv][h8 + 4][jl] = w1;
        if (jl == 0) { fs[wv][h8] = fA; fs[wv][h8 + 4] = fB; }
        asm volatile("s_waitcnt lgkmcnt(0)" ::: "memory");

        // V accumulation: lane owns 4 dims of head hv
        float fv = fs[wv][hv];
        acc0 *= fv; acc1 *= fv; acc2 *= fv; acc3 *= fv;
        for (int j = 0; j < cc; j++) {
            float wj = ws[wv][hv][j];
            uint2 raw = *(const uint2*)(vb + (size_t)cols[wv][c0 + j] * 256 + d0);
            acc0 = fmaf(wj, b2f((u16)(raw.x & 0xffff)), acc0);
            acc1 = fmaf(wj, b2f((u16)(raw.x >> 16)),    acc1);
            acc2 = fmaf(wj, b2f((u16)(raw.y & 0xffff)), acc2);
            acc3 = fmaf(wj, b2f((u16)(raw.y >> 16)),    acc3);
        }
    }

    if (jl == 0) { lsums[wv][h8] = lsA; lsums[wv][h8 + 4] = lsB; }
    asm volatile("s_waitcnt lgkmcnt(0)" ::: "memory");
    float ls = lsums[wv][hv];
    uint2 ov;
    if (cnt > 0) {
        ov.x = (unsigned)f2b(acc0 / ls) | ((unsigned)f2b(acc1 / ls) << 16);
        ov.y = (unsigned)f2b(acc2 / ls) | ((unsigned)f2b(acc3 / ls) << 16);
    } else {
        ov.x = 0u; ov.y = 0u;
    }
    *(uint2*)(yb + (size_t)n * 256 + d0) = ov;
}

// ---------------------------------------------------------------------------
// K4 final MFMA GEMM: out = [x | y] @ Wp^T + bp, K=512, fp32 out.
// Wp pre-converted to bf16 by prep -> B-frags loaded lane-direct from
// global (L2-resident), no LDS, no syncthreads.
// ---------------------------------------------------------------------------
__global__ __launch_bounds__(256) void final_kernel(
    const float* __restrict__ x, const u16* __restrict__ yb,
    const u16* __restrict__ wpb, const float* __restrict__ bp,
    float* __restrict__ out)
{
    int t = threadIdx.x;
    int wv = t >> 6, l = t & 63, lr = l & 15, lk = l >> 4;
    int m0 = blockIdx.x * 64 + wv * 16;
    int n0 = blockIdx.y * 64;

    f32x4 acc[4] = {};
    const float* axb = x  + (size_t)(m0 + lr) * 256 + lk * 8;
    const u16*   ayb = yb + (size_t)(m0 + lr) * 256 + lk * 8;
    const short8* wp_ = (const short8*)(wpb + (size_t)(n0 + lr) * 512 + lk * 8);

    #pragma unroll
    for (int kk = 0; kk < 16; kk++) {
        short8 a;
        if (kk < 8) a = load_cvt8(axb + kk * 32);
        else        a = *(const short8*)(ayb + (kk - 8) * 32);
        #pragma unroll
        for (int j = 0; j < 4; j++) {
            short8 b = wp_[(size_t)j * 16 * 64 + kk * 4];   // +16 rows = 16*512 bf16
            acc[j] = __builtin_amdgcn_mfma_f32_16x16x32_bf16(a, b, acc[j], 0, 0, 0);
        }
    }
    #pragma unroll
    for (int j = 0; j < 4; j++)
        #pragma unroll
        for (int r = 0; r < 4; r++) {
            int grow = m0 + lk * 4 + r;
            int gc   = n0 + j * 16 + lr;
            out[(size_t)grow * 256 + gc] = acc[j][r] + bp[gc];
        }
}

// ---------------------------------------------------------------------------
extern "C" void kernel_launch(void* const* d_in, const int* in_sizes, int n_in,
                              void* d_out, int out_size, void* d_ws, size_t ws_size,
                              hipStream_t stream) {
    const float* x  = (const float*)d_in[0];
    const int*   ei = (const int*)d_in[1];
    const float* Wq = (const float*)d_in[2];
    const float* bq = (const float*)d_in[3];
    const float* Wk = (const float*)d_in[4];
    const float* bk = (const float*)d_in[5];
    const float* Wv = (const float*)d_in[6];
    const float* bv = (const float*)d_in[7];
    const float* Wp = (const float*)d_in[8];
    const float* bp = (const float*)d_in[9];
    float* out = (float*)d_out;

    const int D = 256;
    int N = in_sizes[0] / D;       // 4096
    int E = in_sizes[1] / 2;       // 135168

    size_t maskB = (size_t)N * (N >> 5) * sizeof(unsigned);   // 2 MB
    char* ws = (char*)d_ws;
    unsigned* mask  = (unsigned*)ws;
    unsigned* orbuf = (unsigned*)(ws + maskB);                // 64 words
    u16* qbb = (u16*)(ws + maskB + 512);
    u16* kbb = qbb + (size_t)N * D;
    u16* vbb = kbb + (size_t)N * D;
    u16* ybb = vbb + (size_t)N * D;
    u16* wpb = ybb + (size_t)N * D;                           // 131072 bf16

    prep_kernel<<<384, 256, 0, stream>>>(ei, E, (uint4*)ws, (int)(maskB / 16),
                                         orbuf, Wp, wpb);

    scatter_qkv_kernel<<<512, 256, 0, stream>>>(
        ei, E, N, mask, orbuf, x, Wq, Wk, Wv, bq, bk, bv, qbb, kbb, vbb);

    attn_kernel<<<N / 4, 256, 0, stream>>>(mask, qbb, kbb, vbb, ybb, N);

    dim3 gf(N / 64, 4);
    final_kernel<<<gf, 256, 0, stream>>>(x, ybb, wpb, bp, out);
}